// Round 9
// baseline (960.236 us; speedup 1.0000x reference)
//
#include <hip/hip_runtime.h>
#include <hip/hip_bf16.h>
#include <math.h>

#define NVERT 150000
#define NFACE 300000
#define LVOL  192
#define TVB   16     // vertices per block in fused kernel (M = MFMA M exactly)

typedef short v8s __attribute__((ext_vector_type(8)));
typedef float v4f __attribute__((ext_vector_type(4)));

__device__ __forceinline__ float s2f(short s) {
    unsigned int u = ((unsigned int)(unsigned short)s) << 16;
    return __builtin_bit_cast(float, u);
}
__device__ __forceinline__ short f2s(float f) {
    __hip_bfloat16 h = __float2bfloat16(f);
    return __builtin_bit_cast(short, h);
}
__device__ __forceinline__ float lrelu(float x) { return x > 0.f ? x : 0.15f * x; }

// dtype-agnostic scalar load: bf==1 -> bf16 buffer, bf==0 -> fp32 buffer
__device__ __forceinline__ float ldf(const void* __restrict__ p, int i, int bf) {
    return bf ? s2f(((const short*)p)[i]) : ((const float*)p)[i];
}

// ---- detect: if v is bf16, all leading values are in [-0.9,0.9]; fp32-as-bf16 -> garbage ----
__global__ void detect_kernel(const void* __restrict__ v, int* __restrict__ flag) {
    if (threadIdx.x == 0 && blockIdx.x == 0) {
        const short* b = (const short*)v;
        int ok = 1;
        for (int i = 0; i < 256; i++) {
            float x = s2f(b[i]);
            if (!(fabsf(x) <= 1.0f)) { ok = 0; break; }
        }
        *flag = ok;
    }
}

// ---------------- vertex normals: scatter-add face cross products ----------------
__global__ __launch_bounds__(256) void normals_kernel(const void* __restrict__ v,
                                                      const int* __restrict__ f,
                                                      float* __restrict__ n_accum,
                                                      const int* __restrict__ flag) {
    const int bf = *flag;
    int ft = blockIdx.x * 256 + threadIdx.x;
    if (ft >= NFACE) return;
    int i0 = f[ft * 3 + 0], i1 = f[ft * 3 + 1], i2 = f[ft * 3 + 2];
    float p0x = ldf(v, i0 * 3 + 0, bf), p0y = ldf(v, i0 * 3 + 1, bf), p0z = ldf(v, i0 * 3 + 2, bf);
    float p1x = ldf(v, i1 * 3 + 0, bf), p1y = ldf(v, i1 * 3 + 1, bf), p1z = ldf(v, i1 * 3 + 2, bf);
    float p2x = ldf(v, i2 * 3 + 0, bf), p2y = ldf(v, i2 * 3 + 1, bf), p2z = ldf(v, i2 * 3 + 2, bf);
    float e1x = p1x - p0x, e1y = p1y - p0y, e1z = p1z - p0z;
    float e2x = p2x - p0x, e2y = p2y - p0y, e2z = p2z - p0z;
    float cx = e1y * e2z - e1z * e2y;
    float cy = e1z * e2x - e1x * e2z;
    float cz = e1x * e2y - e1y * e2x;
    atomicAdd(&n_accum[i0 * 3 + 0], cx); atomicAdd(&n_accum[i0 * 3 + 1], cy); atomicAdd(&n_accum[i0 * 3 + 2], cz);
    atomicAdd(&n_accum[i1 * 3 + 0], cx); atomicAdd(&n_accum[i1 * 3 + 1], cy); atomicAdd(&n_accum[i1 * 3 + 2], cz);
    atomicAdd(&n_accum[i2 * 3 + 0], cx); atomicAdd(&n_accum[i2 * 3 + 1], cy); atomicAdd(&n_accum[i2 * 3 + 2], cz);
}

// ---------------- 2x avg-pool pyramids (bf16 out) ----------------
__global__ __launch_bounds__(256) void pool1_kernel(const void* __restrict__ vol,
                                                    short* __restrict__ vol1,
                                                    const int* __restrict__ flag) {
    const int bf = *flag;
    int id = blockIdx.x * 256 + threadIdx.x;
    if (id >= 96 * 96 * 96) return;
    int z = id % 96, y = (id / 96) % 96, x = id / (96 * 96);
    float s = 0.f;
    #pragma unroll
    for (int a = 0; a < 2; a++)
        #pragma unroll
        for (int b = 0; b < 2; b++)
            #pragma unroll
            for (int c = 0; c < 2; c++)
                s += ldf(vol, (2 * x + a) * (LVOL * LVOL) + (2 * y + b) * LVOL + (2 * z + c), bf);
    vol1[id] = f2s(s * 0.125f);
}

__global__ __launch_bounds__(256) void pool2_kernel(const short* __restrict__ vol1,
                                                    short* __restrict__ vol2) {
    int id = blockIdx.x * 256 + threadIdx.x;
    if (id >= 48 * 48 * 48) return;
    int z = id % 48, y = (id / 48) % 48, x = id / (48 * 48);
    float s = 0.f;
    #pragma unroll
    for (int a = 0; a < 2; a++)
        #pragma unroll
        for (int b = 0; b < 2; b++)
            #pragma unroll
            for (int c = 0; c < 2; c++)
                s += s2f(vol1[(2 * x + a) * (96 * 96) + (2 * y + b) * 96 + (2 * z + c)]);
    vol2[id] = f2s(s * 0.125f);
}

// ---------------- weight prep: bf16 [N][K] transposed tables for fc2/fc3 ----------------
__global__ __launch_bounds__(256) void prep_weights_kernel(
    const void* __restrict__ fc2_w, const void* __restrict__ fc3_w,
    short* __restrict__ fc2T, short* __restrict__ fc3T,
    const int* __restrict__ flag) {
    const int bf = *flag;
    int id = blockIdx.x * 256 + threadIdx.x;
    if (id < 131072) {                     // fc2T[j][k] = fc2_w[k][j]
        int j = id >> 8, k = id & 255;
        fc2T[id] = f2s(ldf(fc2_w, k * 512 + j, bf));
    } else if (id < 262144) {              // fc3T[j][k] = fc3_w[k][j]
        int i = id - 131072;
        int j = i >> 9, k = i & 511;
        fc3T[i] = f2s(ldf(fc3_w, k * 256 + j, bf));
    }
}

// ---------------- combined conv+lfc weights (no activation between them!) ----------------
// Wcomb[j][k] = sum_o conv_w[o][k] * lfc_w[o][j]   (j<128, k<384; k>=375 zero)
// bcomb[j]   = sum_o conv_b[o] * lfc_w[o][j] + lfc_b[j]
__global__ __launch_bounds__(256) void prep_comb_kernel(
    const void* __restrict__ conv_w, const void* __restrict__ lfc_w,
    const void* __restrict__ conv_b, const void* __restrict__ lfc_b,
    short* __restrict__ Wcomb, float* __restrict__ bcomb,
    const int* __restrict__ flag) {
    const int bf = *flag;
    int id = blockIdx.x * 256 + threadIdx.x;
    if (id < 49152) {
        int j = id / 384, k = id - j * 384;
        float acc = 0.f;
        if (k < 375) {
            float a0 = 0.f, a1 = 0.f, a2 = 0.f, a3 = 0.f;
            for (int o = 0; o < 128; o += 4) {
                a0 += ldf(conv_w, (o + 0) * 375 + k, bf) * ldf(lfc_w, (o + 0) * 128 + j, bf);
                a1 += ldf(conv_w, (o + 1) * 375 + k, bf) * ldf(lfc_w, (o + 1) * 128 + j, bf);
                a2 += ldf(conv_w, (o + 2) * 375 + k, bf) * ldf(lfc_w, (o + 2) * 128 + j, bf);
                a3 += ldf(conv_w, (o + 3) * 375 + k, bf) * ldf(lfc_w, (o + 3) * 128 + j, bf);
            }
            acc = (a0 + a1) + (a2 + a3);
        }
        Wcomb[j * 384 + k] = f2s(acc);
    } else if (id < 49152 + 128) {
        int j = id - 49152;
        float acc = ldf(lfc_b, j, bf);
        for (int o = 0; o < 128; o++) acc += ldf(conv_b, o, bf) * ldf(lfc_w, o * 128 + j, bf);
        bcomb[j] = acc;
    }
}

// ---------------- fused per-vertex MFMA pipeline (16 verts / block, 5 blocks/CU) ----------------
__global__ __launch_bounds__(256, 5) void fused_mfma_kernel(
    const void* __restrict__ v,
    const float* __restrict__ n_accum,
    const void* __restrict__ volume,
    const short* __restrict__ vol1,
    const short* __restrict__ vol2,
    const short* __restrict__ Wcomb,
    const float* __restrict__ bcomb,
    const short* __restrict__ fc2T,
    const short* __restrict__ fc3T,
    const void* __restrict__ fc1_w, const void* __restrict__ fc1_b,
    const void* __restrict__ fc2_b, const void* __restrict__ fc3_b,
    const void* __restrict__ fc4_w, const void* __restrict__ fc4_b,
    void* __restrict__ out,
    const int* __restrict__ flag)
{
    __shared__ __align__(16) char smem[27904];
    short* sX    = (short*)smem;                 // [16][264]  fc1 out | x_local; later fc3 out (s3)
    short* sCube = (short*)(smem + 8448);        // [16][392]  cubes (region B)
    short* sH    = (short*)(smem + 8448);        // [16][520]  fc2 out (aliases sCube)
    short* s3    = (short*)smem;                 // [16][264]  fc3 out (aliases sX)
    float* sIn6  = (float*)(smem + 25088);       // [16][8]
    int*   sIdx  = (int*)(smem + 25600);         // [16][12]
    short* sW4   = (short*)(smem + 26368);       // [3][256] fc4 weights transposed

    const int bf = *flag;
    const int t = threadIdx.x;
    const int base = blockIdx.x * TVB;
    const int w = t >> 6, L = t & 63, q = L >> 4, ln = L & 15;

    // ---- stage fc4 weights into LDS (once) ----
    for (int i = t; i < 768; i += 256) {
        int j = i >> 8, k = i & 255;
        sW4[i] = f2s(ldf(fc4_w, k * 3 + j, bf));
    }

    // ---- step 1: vertex load, normal normalize, cube indices ----
    if (t < TVB) {
        int vert = base + t;
        float vx = 0.f, vy = 0.f, vz = 0.f, nx = 0.f, ny = 0.f, nz = 0.f;
        if (vert < NVERT) {
            vx = ldf(v, vert * 3 + 0, bf); vy = ldf(v, vert * 3 + 1, bf); vz = ldf(v, vert * 3 + 2, bf);
            nx = n_accum[vert * 3 + 0]; ny = n_accum[vert * 3 + 1]; nz = n_accum[vert * 3 + 2];
        }
        float inv = 1.0f / fmaxf(sqrtf(nx * nx + ny * ny + nz * nz), 1e-12f);
        sIn6[t * 8 + 0] = vx; sIn6[t * 8 + 1] = vy; sIn6[t * 8 + 2] = vz;
        sIn6[t * 8 + 3] = nx * inv; sIn6[t * 8 + 4] = ny * inv; sIn6[t * 8 + 5] = nz * inv;
        float fx = (vx + 1.0f) * 192.0f, fy = (vy + 1.0f) * 192.0f, fz = (vz + 1.0f) * 192.0f;
        #pragma unroll
        for (int n = 0; n < 3; n++) {
            float scl = (n == 0) ? 0.5f : (n == 1 ? 0.25f : 0.125f);
            int lim = (LVOL >> n) - 3;
            int cx = (int)rintf(fx * scl), cy = (int)rintf(fy * scl), cz = (int)rintf(fz * scl);
            cx = min(max(cx, 2), lim); cy = min(max(cy, 2), lim); cz = min(max(cz, 2), lim);
            sIdx[t * 12 + n * 4 + 0] = cx; sIdx[t * 12 + n * 4 + 1] = cy; sIdx[t * 12 + n * 4 + 2] = cz;
        }
    }
    __syncthreads();

    // ---- fc1 (6 -> 128): 16x128 outputs / 256 threads = 8 iters ----
    #pragma unroll
    for (int p = 0; p < 8; p++) {
        int idx = p * 256 + t, vi = idx >> 7, c = idx & 127;
        float acc = ldf(fc1_b, c, bf);
        #pragma unroll
        for (int r = 0; r < 6; r++) acc += sIn6[vi * 8 + r] * ldf(fc1_w, r * 128 + c, bf);
        sX[vi * 264 + c] = f2s(lrelu(acc));
    }

    // ---- cube gather: one task per (vert, level, di, dj) = 5 contiguous z samples ----
    for (int idx = t; idx < TVB * 75; idx += 256) {
        int vert = idx / 75;
        int r75  = idx - vert * 75;
        int n    = r75 / 25;
        int dd   = r75 - n * 25;
        int di   = dd / 5, dj = dd - di * 5;
        int cx = sIdx[vert * 12 + n * 4 + 0] + di - 2;
        int cy = sIdx[vert * 12 + n * 4 + 1] + dj - 2;
        int cz = sIdx[vert * 12 + n * 4 + 2];
        short* dst = &sCube[vert * 392 + n * 125 + dd * 5];
        if (n == 0) {
            int b0 = (cx * LVOL + cy) * LVOL + (cz - 2);
            if (bf) {
                const short* vp = (const short*)volume;
                #pragma unroll
                for (int i = 0; i < 5; i++) dst[i] = vp[b0 + i];
            } else {
                const float* vp = (const float*)volume;
                #pragma unroll
                for (int i = 0; i < 5; i++) dst[i] = f2s(vp[b0 + i]);
            }
        } else {
            const short* lvl = (n == 1) ? vol1 : vol2;
            int dim = (n == 1) ? 96 : 48;
            int b0 = (cx * dim + cy) * dim + (cz - 2);
            #pragma unroll
            for (int i = 0; i < 5; i++) dst[i] = lvl[b0 + i];
        }
    }
    // zero-pad K 375..383
    for (int idx = t; idx < TVB * 9; idx += 256) {
        int vert = idx / 9, rr = idx - vert * 9;
        sCube[vert * 392 + 375 + rr] = 0;
    }
    __syncthreads();

    // ---- combined conv+lfc GEMM: [16x384] @ Wcomb^T -> sX cols 128..255 ----
    // 4 waves x 2 tiles x 16 cols = 128 output columns
    #pragma unroll
    for (int nt = 0; nt < 2; nt++) {
        int col = w * 32 + nt * 16 + ln;
        v4f acc = {0.f, 0.f, 0.f, 0.f};
        #pragma unroll
        for (int k0 = 0; k0 < 12; k0++) {
            v8s b = *(const v8s*)&Wcomb[col * 384 + k0 * 32 + q * 8];
            v8s a = *(const v8s*)&sCube[ln * 392 + k0 * 32 + q * 8];
            acc = __builtin_amdgcn_mfma_f32_16x16x32_bf16(a, b, acc, 0, 0, 0);
        }
        float bias = bcomb[col];
        #pragma unroll
        for (int r = 0; r < 4; r++)
            sX[(q * 4 + r) * 264 + 128 + col] = f2s(acc[r] + bias);
    }
    __syncthreads();

    // ---- fc2 GEMM: [16x256] @ fc2T^T -> sH [16][512], leaky; A hoisted ----
    {
        v8s a0[8];
        #pragma unroll
        for (int k0 = 0; k0 < 8; k0++)
            a0[k0] = *(const v8s*)&sX[ln * 264 + k0 * 32 + q * 8];
        #pragma unroll
        for (int nt = 0; nt < 8; nt++) {
            int col = w * 128 + nt * 16 + ln;
            const short* bb = fc2T + col * 256;
            v4f acc = {0.f, 0.f, 0.f, 0.f};
            #pragma unroll
            for (int k0 = 0; k0 < 8; k0++) {
                v8s b = *(const v8s*)(bb + k0 * 32 + q * 8);
                acc = __builtin_amdgcn_mfma_f32_16x16x32_bf16(a0[k0], b, acc, 0, 0, 0);
            }
            float bias = ldf(fc2_b, col, bf);
            #pragma unroll
            for (int r = 0; r < 4; r++)
                sH[(q * 4 + r) * 520 + col] = f2s(lrelu(acc[r] + bias));
        }
    }
    __syncthreads();

    // ---- fc3 GEMM: [16x512] @ fc3T^T -> s3 [16][256], leaky ----
    {
        #pragma unroll
        for (int nt = 0; nt < 4; nt++) {
            int col = w * 64 + nt * 16 + ln;
            v4f acc = {0.f, 0.f, 0.f, 0.f};
            #pragma unroll
            for (int half = 0; half < 2; half++) {
                const short* bb = fc3T + col * 512 + half * 256;
                #pragma unroll
                for (int k0 = 0; k0 < 8; k0++) {
                    v8s b = *(const v8s*)(bb + k0 * 32 + q * 8);
                    v8s a = *(const v8s*)&sH[ln * 520 + half * 256 + k0 * 32 + q * 8];
                    acc = __builtin_amdgcn_mfma_f32_16x16x32_bf16(a, b, acc, 0, 0, 0);
                }
            }
            float bias = ldf(fc3_b, col, bf);
            #pragma unroll
            for (int r = 0; r < 4; r++)
                s3[(q * 4 + r) * 264 + col] = f2s(lrelu(acc[r] + bias));
        }
    }
    __syncthreads();

    // ---- fc4 (256 -> 3) + tanh*0.1 + residual; 16 threads per vertex; weights from LDS ----
    {
        int vi = t >> 4, l = t & 15;
        float p0 = 0.f, p1 = 0.f, p2 = 0.f;
        for (int k = l; k < 256; k += 16) {
            float a = s2f(s3[vi * 264 + k]);
            p0 += a * s2f(sW4[0 * 256 + k]);
            p1 += a * s2f(sW4[1 * 256 + k]);
            p2 += a * s2f(sW4[2 * 256 + k]);
        }
        #pragma unroll
        for (int s = 8; s; s >>= 1) {
            p0 += __shfl_down(p0, s, 16);
            p1 += __shfl_down(p1, s, 16);
            p2 += __shfl_down(p2, s, 16);
        }
        if (l == 0) {
            int vert = base + vi;
            if (vert < NVERT) {
                float o0 = sIn6[vi * 8 + 0] + 0.1f * tanhf(p0 + ldf(fc4_b, 0, bf));
                float o1 = sIn6[vi * 8 + 1] + 0.1f * tanhf(p1 + ldf(fc4_b, 1, bf));
                float o2 = sIn6[vi * 8 + 2] + 0.1f * tanhf(p2 + ldf(fc4_b, 2, bf));
                if (bf) {
                    short* ob = (short*)out;
                    ob[vert * 3 + 0] = f2s(o0);
                    ob[vert * 3 + 1] = f2s(o1);
                    ob[vert * 3 + 2] = f2s(o2);
                } else {
                    float* of = (float*)out;
                    of[vert * 3 + 0] = o0;
                    of[vert * 3 + 1] = o1;
                    of[vert * 3 + 2] = o2;
                }
            }
        }
    }
}

extern "C" void kernel_launch(void* const* d_in, const int* in_sizes, int n_in,
                              void* d_out, int out_size, void* d_ws, size_t ws_size,
                              hipStream_t stream) {
    const void* v      = d_in[0];
    const int*  f      = (const int*)d_in[1];
    const void* volume = d_in[2];
    const void* fc1_w  = d_in[3];
    const void* fc1_b  = d_in[4];
    const void* fc2_w  = d_in[5];
    const void* fc2_b  = d_in[6];
    const void* fc3_w  = d_in[7];
    const void* fc3_b  = d_in[8];
    const void* fc4_w  = d_in[9];
    const void* fc4_b  = d_in[10];
    const void* conv_w = d_in[11];
    const void* conv_b = d_in[12];
    const void* lfc_w  = d_in[13];
    const void* lfc_b  = d_in[14];

    // ws layout (~4.41 MB total, proven in R8)
    char* wsb = (char*)d_ws;
    int*   flag    = (int*)wsb;                    //        64 B
    float* n_accum = (float*)(wsb + 64);           // 1,800,000 B
    short* vol1    = (short*)(wsb + 1800064);      // 1,769,472 B (bf16)
    short* vol2    = (short*)(wsb + 3569536);      //   221,184 B (bf16)
    short* Wcomb   = (short*)(wsb + 3790720);      //    98,304 B
    float* bcomb   = (float*)(wsb + 3889024);      //       512 B
    short* fc2T    = (short*)(wsb + 3889536);      //   262,144 B
    short* fc3T    = (short*)(wsb + 4151680);      //   262,144 B  -> end 4,413,824 B

    hipMemsetAsync(n_accum, 0, NVERT * 3 * sizeof(float), stream);

    detect_kernel<<<1, 64, 0, stream>>>(v, flag);
    normals_kernel<<<(NFACE + 255) / 256, 256, 0, stream>>>(v, f, n_accum, flag);
    pool1_kernel<<<(96 * 96 * 96) / 256, 256, 0, stream>>>(volume, vol1, flag);
    pool2_kernel<<<(48 * 48 * 48) / 256, 256, 0, stream>>>(vol1, vol2);
    prep_weights_kernel<<<(262144 + 255) / 256, 256, 0, stream>>>(fc2_w, fc3_w, fc2T, fc3T, flag);
    prep_comb_kernel<<<(49152 + 128 + 255) / 256, 256, 0, stream>>>(
        conv_w, lfc_w, conv_b, lfc_b, Wcomb, bcomb, flag);

    fused_mfma_kernel<<<(NVERT + TVB - 1) / TVB, 256, 0, stream>>>(
        v, n_accum, volume, vol1, vol2, Wcomb, bcomb, fc2T, fc3T,
        fc1_w, fc1_b, fc2_b, fc3_b, fc4_w, fc4_b,
        d_out, flag);
}

// Round 10
// 702.742 us; speedup vs baseline: 1.3664x; 1.3664x over previous
//
#include <hip/hip_runtime.h>
#include <hip/hip_bf16.h>
#include <math.h>

#define NVERT 150000
#define NFACE 300000
#define LVOL  192
#define TVB   32     // vertices per block in fused kernel (R8-proven)

// mega_prep block-range partition
#define NB_NORM  1172                 // (300000+255)/256
#define NB_POOL1 3456                 // 884736/256
#define NB_PW    1024                 // 262144/256
#define NB_PC    193                  // (49152+128+255)/256
#define PC_START (NB_NORM + NB_POOL1 + NB_PW)
#define NB_MEGA  (NB_NORM + NB_POOL1 + NB_PW + NB_PC)

typedef short v8s __attribute__((ext_vector_type(8)));
typedef float v4f __attribute__((ext_vector_type(4)));

__device__ __forceinline__ float s2f(short s) {
    unsigned int u = ((unsigned int)(unsigned short)s) << 16;
    return __builtin_bit_cast(float, u);
}
__device__ __forceinline__ short f2s(float f) {
    __hip_bfloat16 h = __float2bfloat16(f);
    return __builtin_bit_cast(short, h);
}
__device__ __forceinline__ float lrelu(float x) { return x > 0.f ? x : 0.15f * x; }

// dtype-agnostic scalar load: bf==1 -> bf16 buffer, bf==0 -> fp32 buffer
__device__ __forceinline__ float ldf(const void* __restrict__ p, int i, int bf) {
    return bf ? s2f(((const short*)p)[i]) : ((const float*)p)[i];
}

// ---- detect (parallel): if v is bf16, leading values are in [-1,1]; fp32-as-bf16 -> garbage ----
__global__ void detect_kernel(const void* __restrict__ v, int* __restrict__ flag) {
    __shared__ int s_ok;
    int t = threadIdx.x;
    if (t == 0) s_ok = 1;
    __syncthreads();
    float x = s2f(((const short*)v)[t]);
    if (!(fabsf(x) <= 1.0f)) atomicAnd(&s_ok, 0);
    __syncthreads();
    if (t == 0) *flag = s_ok;
}

// ---------------- mega prep: normals | pool1 | fc2T/fc3T transpose | Wcomb/bcomb ----------------
__global__ __launch_bounds__(256) void mega_prep_kernel(
    const void* __restrict__ v, const int* __restrict__ f, float* __restrict__ n_accum,
    const void* __restrict__ volume, short* __restrict__ vol1,
    const void* __restrict__ fc2_w, const void* __restrict__ fc3_w,
    short* __restrict__ fc2T, short* __restrict__ fc3T,
    const void* __restrict__ conv_w, const void* __restrict__ lfc_w,
    const void* __restrict__ conv_b, const void* __restrict__ lfc_b,
    short* __restrict__ Wcomb, float* __restrict__ bcomb,
    const int* __restrict__ flag)
{
    const int bf = *flag;
    const int bid = blockIdx.x;
    const int t = threadIdx.x;

    if (bid < NB_NORM) {
        // ---- vertex normals: scatter-add face cross products ----
        int ft = bid * 256 + t;
        if (ft >= NFACE) return;
        int i0 = f[ft * 3 + 0], i1 = f[ft * 3 + 1], i2 = f[ft * 3 + 2];
        float p0x = ldf(v, i0 * 3 + 0, bf), p0y = ldf(v, i0 * 3 + 1, bf), p0z = ldf(v, i0 * 3 + 2, bf);
        float p1x = ldf(v, i1 * 3 + 0, bf), p1y = ldf(v, i1 * 3 + 1, bf), p1z = ldf(v, i1 * 3 + 2, bf);
        float p2x = ldf(v, i2 * 3 + 0, bf), p2y = ldf(v, i2 * 3 + 1, bf), p2z = ldf(v, i2 * 3 + 2, bf);
        float e1x = p1x - p0x, e1y = p1y - p0y, e1z = p1z - p0z;
        float e2x = p2x - p0x, e2y = p2y - p0y, e2z = p2z - p0z;
        float cx = e1y * e2z - e1z * e2y;
        float cy = e1z * e2x - e1x * e2z;
        float cz = e1x * e2y - e1y * e2x;
        atomicAdd(&n_accum[i0 * 3 + 0], cx); atomicAdd(&n_accum[i0 * 3 + 1], cy); atomicAdd(&n_accum[i0 * 3 + 2], cz);
        atomicAdd(&n_accum[i1 * 3 + 0], cx); atomicAdd(&n_accum[i1 * 3 + 1], cy); atomicAdd(&n_accum[i1 * 3 + 2], cz);
        atomicAdd(&n_accum[i2 * 3 + 0], cx); atomicAdd(&n_accum[i2 * 3 + 1], cy); atomicAdd(&n_accum[i2 * 3 + 2], cz);
    } else if (bid < NB_NORM + NB_POOL1) {
        // ---- pool1: 192^3 -> 96^3 avg (bf16 out) ----
        int id = (bid - NB_NORM) * 256 + t;
        int z = id % 96, y = (id / 96) % 96, x = id / (96 * 96);
        float s = 0.f;
        #pragma unroll
        for (int a = 0; a < 2; a++)
            #pragma unroll
            for (int b = 0; b < 2; b++)
                #pragma unroll
                for (int c = 0; c < 2; c++)
                    s += ldf(volume, (2 * x + a) * (LVOL * LVOL) + (2 * y + b) * LVOL + (2 * z + c), bf);
        vol1[id] = f2s(s * 0.125f);
    } else if (bid < PC_START) {
        // ---- fc2T[j][k] = fc2_w[k][j]; fc3T[j][k] = fc3_w[k][j] ----
        int id = (bid - NB_NORM - NB_POOL1) * 256 + t;
        if (id < 131072) {
            int j = id >> 8, k = id & 255;
            fc2T[id] = f2s(ldf(fc2_w, k * 512 + j, bf));
        } else {
            int i = id - 131072;
            int j = i >> 9, k = i & 511;
            fc3T[i] = f2s(ldf(fc3_w, k * 256 + j, bf));
        }
    } else {
        // ---- combined conv+lfc weights ----
        int id = (bid - PC_START) * 256 + t;
        if (id < 49152) {
            int j = id / 384, k = id - j * 384;
            float acc = 0.f;
            if (k < 375) {
                float a0 = 0.f, a1 = 0.f, a2 = 0.f, a3 = 0.f;
                for (int o = 0; o < 128; o += 4) {
                    a0 += ldf(conv_w, (o + 0) * 375 + k, bf) * ldf(lfc_w, (o + 0) * 128 + j, bf);
                    a1 += ldf(conv_w, (o + 1) * 375 + k, bf) * ldf(lfc_w, (o + 1) * 128 + j, bf);
                    a2 += ldf(conv_w, (o + 2) * 375 + k, bf) * ldf(lfc_w, (o + 2) * 128 + j, bf);
                    a3 += ldf(conv_w, (o + 3) * 375 + k, bf) * ldf(lfc_w, (o + 3) * 128 + j, bf);
                }
                acc = (a0 + a1) + (a2 + a3);
            }
            Wcomb[j * 384 + k] = f2s(acc);
        } else if (id < 49152 + 128) {
            int j = id - 49152;
            float acc = ldf(lfc_b, j, bf);
            for (int o = 0; o < 128; o++) acc += ldf(conv_b, o, bf) * ldf(lfc_w, o * 128 + j, bf);
            bcomb[j] = acc;
        }
    }
}

// ---------------- pool2: 96^3 -> 48^3 (depends on vol1) ----------------
__global__ __launch_bounds__(256) void pool2_kernel(const short* __restrict__ vol1,
                                                    short* __restrict__ vol2) {
    int id = blockIdx.x * 256 + threadIdx.x;
    if (id >= 48 * 48 * 48) return;
    int z = id % 48, y = (id / 48) % 48, x = id / (48 * 48);
    float s = 0.f;
    #pragma unroll
    for (int a = 0; a < 2; a++)
        #pragma unroll
        for (int b = 0; b < 2; b++)
            #pragma unroll
            for (int c = 0; c < 2; c++)
                s += s2f(vol1[(2 * x + a) * (96 * 96) + (2 * y + b) * 96 + (2 * z + c)]);
    vol2[id] = f2s(s * 0.125f);
}

// ---------------- fused per-vertex MFMA pipeline (32 verts / block) ----------------
// Phase 1 is barrier-free: gather (HBM, longest latency) issues from instruction #1;
// index math inlined (v loads L1-hot); fc1 normalizes per-thread (vertex-per-thread layout).
__global__ __launch_bounds__(256, 3) void fused_mfma_kernel(
    const void* __restrict__ v,
    const float* __restrict__ n_accum,
    const void* __restrict__ volume,
    const short* __restrict__ vol1,
    const short* __restrict__ vol2,
    const short* __restrict__ Wcomb,
    const float* __restrict__ bcomb,
    const short* __restrict__ fc2T,
    const short* __restrict__ fc3T,
    const void* __restrict__ fc1_w, const void* __restrict__ fc1_b,
    const void* __restrict__ fc2_b, const void* __restrict__ fc3_b,
    const void* __restrict__ fc4_w, const void* __restrict__ fc4_b,
    void* __restrict__ out,
    const int* __restrict__ flag)
{
    __shared__ __align__(16) char smem[51712];
    short* sX    = (short*)smem;                 // [32][264]  fc1 | x_local; later fc3 out (s3)
    short* sCube = (short*)(smem + 16896);       // [32][392]  cubes (region B)
    short* sH    = (short*)(smem + 16896);       // [32][520]  fc2 out (aliases sCube)
    short* s3    = (short*)smem;                 // [32][264]  fc3 out (aliases sX)
    short* sW4   = (short*)(smem + 50176);       // [3][256]   fc4 weights transposed

    const int bf = *flag;
    const int t = threadIdx.x;
    const int base = blockIdx.x * TVB;
    const int w = t >> 6, L = t & 63, q = L >> 4, ln = L & 15;

    // ---- cube gather FIRST: one task per (vert, level, di, dj) = 5 contiguous z samples ----
    for (int idx = t; idx < TVB * 75; idx += 256) {
        int vl  = idx / 75;
        int r75 = idx - vl * 75;
        int n   = r75 / 25;
        int dd  = r75 - n * 25;
        int di  = dd / 5, dj = dd - di * 5;
        int vert = base + vl;
        short* dst = &sCube[vl * 392 + n * 125 + dd * 5];
        if (vert < NVERT) {
            float vx = ldf(v, vert * 3 + 0, bf);
            float vy = ldf(v, vert * 3 + 1, bf);
            float vz = ldf(v, vert * 3 + 2, bf);
            // ((v+1)*192)*2^-n-1 == (v+1)*{96,48,24} exactly (pow2 scaling commutes with RN)
            float scl = (n == 0) ? 96.0f : (n == 1 ? 48.0f : 24.0f);
            int lim = (LVOL >> n) - 3;
            int cx = (int)rintf((vx + 1.0f) * scl);
            int cy = (int)rintf((vy + 1.0f) * scl);
            int cz = (int)rintf((vz + 1.0f) * scl);
            cx = min(max(cx, 2), lim) + di - 2;
            cy = min(max(cy, 2), lim) + dj - 2;
            cz = min(max(cz, 2), lim);
            if (n == 0) {
                int b0 = (cx * LVOL + cy) * LVOL + (cz - 2);
                if (bf) {
                    const short* vp = (const short*)volume;
                    #pragma unroll
                    for (int i = 0; i < 5; i++) dst[i] = vp[b0 + i];
                } else {
                    const float* vp = (const float*)volume;
                    #pragma unroll
                    for (int i = 0; i < 5; i++) dst[i] = f2s(vp[b0 + i]);
                }
            } else {
                const short* lvl = (n == 1) ? vol1 : vol2;
                int dim = (n == 1) ? 96 : 48;
                int b0 = (cx * dim + cy) * dim + (cz - 2);
                #pragma unroll
                for (int i = 0; i < 5; i++) dst[i] = lvl[b0 + i];
            }
        } else {
            #pragma unroll
            for (int i = 0; i < 5; i++) dst[i] = 0;
        }
    }
    // zero-pad K 375..383
    for (int idx = t; idx < TVB * 9; idx += 256) {
        int vl = idx / 9, rr = idx - vl * 9;
        sCube[vl * 392 + 375 + rr] = 0;
    }

    // ---- stage fc4 weights into LDS ----
    for (int i = t; i < 768; i += 256) {
        int j = i >> 8, k = i & 255;
        sW4[i] = f2s(ldf(fc4_w, k * 3 + j, bf));
    }

    // ---- fc1 (6 -> 128): one vertex per thread, 16 cols each; normalize computed once ----
    {
        int vi = t & 31, cb = (t >> 5) * 16;
        int vert = base + vi;
        float i0 = 0.f, i1 = 0.f, i2 = 0.f, i3 = 0.f, i4 = 0.f, i5 = 0.f;
        if (vert < NVERT) {
            i0 = ldf(v, vert * 3 + 0, bf);
            i1 = ldf(v, vert * 3 + 1, bf);
            i2 = ldf(v, vert * 3 + 2, bf);
            float nx = n_accum[vert * 3 + 0];
            float ny = n_accum[vert * 3 + 1];
            float nz = n_accum[vert * 3 + 2];
            float inv = 1.0f / fmaxf(sqrtf(nx * nx + ny * ny + nz * nz), 1e-12f);
            i3 = nx * inv; i4 = ny * inv; i5 = nz * inv;
        }
        #pragma unroll
        for (int i = 0; i < 16; i++) {
            int c = cb + i;
            float acc = ldf(fc1_b, c, bf)
                      + i0 * ldf(fc1_w, 0 * 128 + c, bf)
                      + i1 * ldf(fc1_w, 1 * 128 + c, bf)
                      + i2 * ldf(fc1_w, 2 * 128 + c, bf)
                      + i3 * ldf(fc1_w, 3 * 128 + c, bf)
                      + i4 * ldf(fc1_w, 4 * 128 + c, bf)
                      + i5 * ldf(fc1_w, 5 * 128 + c, bf);
            sX[vi * 264 + c] = f2s(lrelu(acc));
        }
    }
    __syncthreads();

    // ---- combined conv+lfc GEMM: [32x384] @ Wcomb^T -> sX cols 128..255 ----
    #pragma unroll
    for (int nt = 0; nt < 2; nt++) {
        int col = w * 32 + nt * 16 + ln;
        v4f acc0 = {0.f, 0.f, 0.f, 0.f}, acc1 = {0.f, 0.f, 0.f, 0.f};
        #pragma unroll
        for (int k0 = 0; k0 < 12; k0++) {
            v8s b  = *(const v8s*)&Wcomb[col * 384 + k0 * 32 + q * 8];
            v8s a0 = *(const v8s*)&sCube[ln * 392 + k0 * 32 + q * 8];
            v8s a1 = *(const v8s*)&sCube[(16 + ln) * 392 + k0 * 32 + q * 8];
            acc0 = __builtin_amdgcn_mfma_f32_16x16x32_bf16(a0, b, acc0, 0, 0, 0);
            acc1 = __builtin_amdgcn_mfma_f32_16x16x32_bf16(a1, b, acc1, 0, 0, 0);
        }
        float bias = bcomb[col];
        #pragma unroll
        for (int r = 0; r < 4; r++) {
            sX[(q * 4 + r) * 264 + 128 + col]      = f2s(acc0[r] + bias);
            sX[(16 + q * 4 + r) * 264 + 128 + col] = f2s(acc1[r] + bias);
        }
    }
    __syncthreads();

    // ---- fc2 GEMM: [32x256] @ fc2T^T -> sH [32][512], leaky; A hoisted ----
    {
        v8s a0[8], a1[8];
        #pragma unroll
        for (int k0 = 0; k0 < 8; k0++) {
            a0[k0] = *(const v8s*)&sX[ln * 264 + k0 * 32 + q * 8];
            a1[k0] = *(const v8s*)&sX[(16 + ln) * 264 + k0 * 32 + q * 8];
        }
        #pragma unroll
        for (int nt = 0; nt < 8; nt++) {
            int col = w * 128 + nt * 16 + ln;
            const short* bb = fc2T + col * 256;
            v4f acc0 = {0.f, 0.f, 0.f, 0.f}, acc1 = {0.f, 0.f, 0.f, 0.f};
            #pragma unroll
            for (int k0 = 0; k0 < 8; k0++) {
                v8s b = *(const v8s*)(bb + k0 * 32 + q * 8);
                acc0 = __builtin_amdgcn_mfma_f32_16x16x32_bf16(a0[k0], b, acc0, 0, 0, 0);
                acc1 = __builtin_amdgcn_mfma_f32_16x16x32_bf16(a1[k0], b, acc1, 0, 0, 0);
            }
            float bias = ldf(fc2_b, col, bf);
            #pragma unroll
            for (int r = 0; r < 4; r++) {
                sH[(q * 4 + r) * 520 + col]      = f2s(lrelu(acc0[r] + bias));
                sH[(16 + q * 4 + r) * 520 + col] = f2s(lrelu(acc1[r] + bias));
            }
        }
    }
    __syncthreads();

    // ---- fc3 GEMM: [32x512] @ fc3T^T -> s3 [32][256], leaky ----
    {
        #pragma unroll
        for (int nt = 0; nt < 4; nt++) {
            int col = w * 64 + nt * 16 + ln;
            v4f acc0 = {0.f, 0.f, 0.f, 0.f}, acc1 = {0.f, 0.f, 0.f, 0.f};
            #pragma unroll
            for (int half = 0; half < 2; half++) {
                const short* bb = fc3T + col * 512 + half * 256;
                #pragma unroll
                for (int k0 = 0; k0 < 8; k0++) {
                    v8s b  = *(const v8s*)(bb + k0 * 32 + q * 8);
                    v8s a0 = *(const v8s*)&sH[ln * 520 + half * 256 + k0 * 32 + q * 8];
                    v8s a1 = *(const v8s*)&sH[(16 + ln) * 520 + half * 256 + k0 * 32 + q * 8];
                    acc0 = __builtin_amdgcn_mfma_f32_16x16x32_bf16(a0, b, acc0, 0, 0, 0);
                    acc1 = __builtin_amdgcn_mfma_f32_16x16x32_bf16(a1, b, acc1, 0, 0, 0);
                }
            }
            float bias = ldf(fc3_b, col, bf);
            #pragma unroll
            for (int r = 0; r < 4; r++) {
                s3[(q * 4 + r) * 264 + col]      = f2s(lrelu(acc0[r] + bias));
                s3[(16 + q * 4 + r) * 264 + col] = f2s(lrelu(acc1[r] + bias));
            }
        }
    }
    __syncthreads();

    // ---- fc4 (256 -> 3) + tanh*0.1 + residual; 8 threads per vertex; weights from LDS ----
    {
        int vi = t >> 3, l = t & 7;
        float p0 = 0.f, p1 = 0.f, p2 = 0.f;
        for (int k = l; k < 256; k += 8) {
            float a = s2f(s3[vi * 264 + k]);
            p0 += a * s2f(sW4[0 * 256 + k]);
            p1 += a * s2f(sW4[1 * 256 + k]);
            p2 += a * s2f(sW4[2 * 256 + k]);
        }
        #pragma unroll
        for (int s = 4; s; s >>= 1) {
            p0 += __shfl_down(p0, s, 8);
            p1 += __shfl_down(p1, s, 8);
            p2 += __shfl_down(p2, s, 8);
        }
        if (l == 0) {
            int vert = base + vi;
            if (vert < NVERT) {
                float vx = ldf(v, vert * 3 + 0, bf);
                float vy = ldf(v, vert * 3 + 1, bf);
                float vz = ldf(v, vert * 3 + 2, bf);
                float o0 = vx + 0.1f * tanhf(p0 + ldf(fc4_b, 0, bf));
                float o1 = vy + 0.1f * tanhf(p1 + ldf(fc4_b, 1, bf));
                float o2 = vz + 0.1f * tanhf(p2 + ldf(fc4_b, 2, bf));
                if (bf) {
                    short* ob = (short*)out;
                    ob[vert * 3 + 0] = f2s(o0);
                    ob[vert * 3 + 1] = f2s(o1);
                    ob[vert * 3 + 2] = f2s(o2);
                } else {
                    float* of = (float*)out;
                    of[vert * 3 + 0] = o0;
                    of[vert * 3 + 1] = o1;
                    of[vert * 3 + 2] = o2;
                }
            }
        }
    }
}

extern "C" void kernel_launch(void* const* d_in, const int* in_sizes, int n_in,
                              void* d_out, int out_size, void* d_ws, size_t ws_size,
                              hipStream_t stream) {
    const void* v      = d_in[0];
    const int*  f      = (const int*)d_in[1];
    const void* volume = d_in[2];
    const void* fc1_w  = d_in[3];
    const void* fc1_b  = d_in[4];
    const void* fc2_w  = d_in[5];
    const void* fc2_b  = d_in[6];
    const void* fc3_w  = d_in[7];
    const void* fc3_b  = d_in[8];
    const void* fc4_w  = d_in[9];
    const void* fc4_b  = d_in[10];
    const void* conv_w = d_in[11];
    const void* conv_b = d_in[12];
    const void* lfc_w  = d_in[13];
    const void* lfc_b  = d_in[14];

    // ws layout (~4.41 MB total, proven in R8)
    char* wsb = (char*)d_ws;
    int*   flag    = (int*)wsb;                    //        64 B
    float* n_accum = (float*)(wsb + 64);           // 1,800,000 B
    short* vol1    = (short*)(wsb + 1800064);      // 1,769,472 B (bf16)
    short* vol2    = (short*)(wsb + 3569536);      //   221,184 B (bf16)
    short* Wcomb   = (short*)(wsb + 3790720);      //    98,304 B
    float* bcomb   = (float*)(wsb + 3889024);      //       512 B
    short* fc2T    = (short*)(wsb + 3889536);      //   262,144 B
    short* fc3T    = (short*)(wsb + 4151680);      //   262,144 B  -> end 4,413,824 B

    hipMemsetAsync(n_accum, 0, NVERT * 3 * sizeof(float), stream);

    detect_kernel<<<1, 256, 0, stream>>>(v, flag);
    mega_prep_kernel<<<NB_MEGA, 256, 0, stream>>>(
        v, f, n_accum, volume, vol1, fc2_w, fc3_w, fc2T, fc3T,
        conv_w, lfc_w, conv_b, lfc_b, Wcomb, bcomb, flag);
    pool2_kernel<<<(48 * 48 * 48) / 256, 256, 0, stream>>>(vol1, vol2);

    fused_mfma_kernel<<<(NVERT + TVB - 1) / TVB, 256, 0, stream>>>(
        v, n_accum, volume, vol1, vol2, Wcomb, bcomb, fc2T, fc3T,
        fc1_w, fc1_b, fc2_b, fc3_b, fc4_w, fc4_b,
        d_out, flag);
}